// Round 2
// baseline (343.659 us; speedup 1.0000x reference)
//
#include <hip/hip_runtime.h>
#include <math.h>

// Problem constants
constexpr int N_TOKENS = 8192;
constexpr int D_MODEL  = 4096;
constexpr int N_EXP    = 256;

// Fused one-shot GEMM: 32 tokens x 256 experts per block, no split-K.
constexpr int BM = 32;              // tokens per block
constexpr int BK = 32;              // K per chunk (= MFMA K)
constexpr int NC = D_MODEL / BK;    // 128 chunks

// ws B layout: [chunk c][plane hi/lo][256 exp x 32 k, XOR-swizzled granules]
constexpr int WPL = N_EXP * BK;     // 8192 ushorts per plane (16 KB)
constexpr int WCH = 2 * WPL;        // 16384 ushorts per chunk (32 KB)

// LDS layout (bytes):
//   [0, 16384)      A fp32, 4 stages x 4096 B  (32 tok x 32 k, source-swizzled)
//   [16384, 114688) B bf16 hi/lo, 3 stages x 32768 B (verbatim wsB chunk image)
constexpr int A_STAGE_F = 1024;         // floats per A stage
constexpr int A_STAGE_U = 2048;         // ushorts per A stage
constexpr int BB_USH    = 4 * A_STAGE_U;        // 8192: ushort offset of B region
constexpr int B_STAGE_U = WCH;                  // 16384 ushorts per B stage
constexpr size_t LDS_BYTES = (size_t)(BB_USH + 3 * B_STAGE_U) * sizeof(unsigned short); // 114688

constexpr size_t WS_NEED = (size_t)NC * WCH * sizeof(unsigned short);  // 4 MB

typedef __attribute__((ext_vector_type(8))) short short8;
typedef __attribute__((ext_vector_type(4))) float f32x4;
typedef unsigned int u32;
typedef const __attribute__((address_space(1))) u32* gas_ptr;
typedef __attribute__((address_space(3))) u32* las_ptr;

static __device__ __forceinline__ unsigned short f2bf(float x) {
    union { float f; unsigned u; } v; v.f = x;
    unsigned r = v.u + 0x7fffu + ((v.u >> 16) & 1u);   // RNE
    return (unsigned short)(r >> 16);
}
static __device__ __forceinline__ float bf2f(unsigned short s) {
    union { unsigned u; float f; } v; v.u = ((unsigned)s) << 16;
    return v.f;
}

// Split 8 fp32 -> bf16 hi (truncate) + bf16 lo (RNE of residual), packed pairs.
static __device__ __forceinline__ void split8(const float4 x0, const float4 x1,
                                              short8& hi, short8& lo) {
    const float xs[8] = {x0.x, x0.y, x0.z, x0.w, x1.x, x1.y, x1.z, x1.w};
    union { u32 u[4]; short8 v; } Hh, Ll;
    #pragma unroll
    for (int p = 0; p < 4; ++p) {
        const u32 u0 = __float_as_uint(xs[2*p]);
        const u32 u1 = __float_as_uint(xs[2*p + 1]);
        Hh.u[p] = (u0 >> 16) | (u1 & 0xffff0000u);
        const float r0 = xs[2*p]     - __uint_as_float(u0 & 0xffff0000u);
        const float r1 = xs[2*p + 1] - __uint_as_float(u1 & 0xffff0000u);
        const u32 b0 = __float_as_uint(r0);
        const u32 b1 = __float_as_uint(r1);
        Ll.u[p] = ((b0 + 0x7fffu + ((b0 >> 16) & 1u)) >> 16) |
                  ((b1 + 0x7fffu + ((b1 >> 16) & 1u)) & 0xffff0000u);
    }
    hi = Hh.v; lo = Ll.v;
}

// ---- W fp32 -> bf16 hi/lo, chunk-major + XOR-swizzled for global_load_lds ----
// Writer is perfectly linear in ws; the granule permutation is applied on the
// *read side* of W (same cache lines, quad-permuted) so ws == LDS image.
__global__ __launch_bounds__(256) void convert_w(
    const float* __restrict__ W, unsigned short* __restrict__ wsB)
{
    const int c    = blockIdx.x >> 2;           // chunk
    const int q    = blockIdx.x & 3;            // expert quarter
    const int t    = threadIdx.x;
    const int e    = q * 64 + (t >> 2);
    const int slot = t & 3;                     // physical 16B granule in row
    const int kq   = slot ^ ((e >> 1) & 3);     // logical k-granule (8 ushorts)

    const float* src = W + (size_t)e * D_MODEL + c * BK + kq * 8;
    const float4 x0 = *(const float4*)src;
    const float4 x1 = *(const float4*)(src + 4);
    const float xs[8] = {x0.x, x0.y, x0.z, x0.w, x1.x, x1.y, x1.z, x1.w};
    short8 vh, vl;
    #pragma unroll
    for (int j = 0; j < 8; ++j) {
        const unsigned short h = f2bf(xs[j]);
        vh[j] = (short)h;
        vl[j] = (short)f2bf(xs[j] - bf2f(h));
    }
    unsigned short* dst = wsB + (size_t)c * WCH + e * 32 + slot * 8;
    *(short8*)dst         = vh;
    *(short8*)(dst + WPL) = vl;
}

// ---- fused GEMM (bf16x3) + sigmoid + group-top2 + coalesced logits ----
// Pipeline: ALL staging via global_load_lds; per-iter group = 8 B-loads + 1
// A-load (fp32). Iteration-atomic counted wait vmcnt(18) keeps 2 iterations in
// flight across barriers; barriers drain lgkm only (never vmcnt). B is
// wave-private (wave stages exactly the experts it reads); A is cross-wave but
// drained one barrier before its consuming iteration (issued at c-3, drained
// by every wave at iter c-1, read at iter c).
__global__ __launch_bounds__(256, 1) void gate_fused(
    const float* __restrict__ H, const unsigned short* __restrict__ wsB,
    float* __restrict__ logits, float* __restrict__ out_idx, float* __restrict__ out_w)
{
    extern __shared__ unsigned short lds[];

    const int t      = threadIdx.x;
    const int L      = t & 63;
    const int w      = t >> 6;          // wave: experts [w*64, w*64+64)
    const int lane16 = L & 15;
    const int g4     = L >> 4;          // k-granule for frag reads
    const int tok0   = blockIdx.x * BM;

    // A staging: thread t fills physical 16B slot (row=t>>3, gp=(t>>1)&3, hp=t&1)
    // of the fp32 A stage. LDS dest is lane-linear (t*16B); the bank-conflict
    // swizzle is applied on the global SOURCE address (m173 pattern):
    //   phys (gp,hp) holds logical (gl = gp ^ ((row>>1)&3), hl = hp ^ (row&1)).
    const int tokA = t >> 3;
    const int gl   = ((t >> 1) & 3) ^ ((tokA >> 1) & 3);
    const int hl   = (t & 1) ^ (tokA & 1);
    const float* srcA = H + (size_t)(tok0 + tokA) * D_MODEL + gl * 8 + hl * 4;

    f32x4 acc[2][4];
    #pragma unroll
    for (int mi = 0; mi < 2; ++mi)
        #pragma unroll
        for (int ni = 0; ni < 4; ++ni) acc[mi][ni] = (f32x4)0.0f;

    auto dmaB = [&](int cc, int s) {
        const unsigned short* src = wsB + (size_t)cc * WCH;
        unsigned short* dst = lds + BB_USH + s * B_STAGE_U;
        #pragma unroll
        for (int p = 0; p < 2; ++p)
            #pragma unroll
            for (int i = 0; i < 4; ++i) {
                const int o = p * WPL + (w * 4 + i) * 512;   // ushort offset
                __builtin_amdgcn_global_load_lds(
                    (gas_ptr)(const void*)(src + o + L * 8),
                    (las_ptr)(void*)(dst + o), 16, 0, 0);
            }
    };

    auto dmaA = [&](int cc, int s) {
        __builtin_amdgcn_global_load_lds(
            (gas_ptr)(const void*)(srcA + (size_t)cc * BK),
            (las_ptr)(void*)(lds + s * A_STAGE_U + w * 512), 16, 0, 0);
    };

    auto compute = [&](int c) {
        const float*          Af = (const float*)(const void*)lds + (c & 3) * A_STAGE_F;
        const unsigned short* Bh = lds + BB_USH + (c % 3) * B_STAGE_U;
        const unsigned short* Bl = Bh + WPL;
        short8 ah[2], al[2];
        #pragma unroll
        for (int mi = 0; mi < 2; ++mi) {
            const int row = mi * 16 + lane16;
            const int gp  = g4 ^ ((row >> 1) & 3);
            const float* ap = Af + row * 32 + gp * 8;
            const int swp = (row & 1) << 2;
            const float4 x0 = *(const float4*)(ap + swp);        // logical k 0..3
            const float4 x1 = *(const float4*)(ap + (swp ^ 4));  // logical k 4..7
            split8(x0, x1, ah[mi], al[mi]);
        }
        #pragma unroll
        for (int ni = 0; ni < 4; ++ni) {
            const int e   = w * 64 + ni * 16 + lane16;
            const int off = e * 32 + ((g4 ^ ((e >> 1) & 3)) << 3);
            const short8 bh = *(const short8*)(Bh + off);
            const short8 bl = *(const short8*)(Bl + off);
            #pragma unroll
            for (int mi = 0; mi < 2; ++mi) {
                acc[mi][ni] = __builtin_amdgcn_mfma_f32_16x16x32_bf16(ah[mi], bh, acc[mi][ni], 0, 0, 0);
                acc[mi][ni] = __builtin_amdgcn_mfma_f32_16x16x32_bf16(ah[mi], bl, acc[mi][ni], 0, 0, 0);
                acc[mi][ni] = __builtin_amdgcn_mfma_f32_16x16x32_bf16(al[mi], bh, acc[mi][ni], 0, 0, 0);
            }
        }
    };

    // Prologue groups: g(-2) = [B(0), A(0), A(1)] (10 ops), g(-1) = [B(1), A(2)]
    // (9 ops). vmcnt(9) drains g(-2); barrier publishes A(0)/A(1) cross-wave.
    dmaB(0, 0);
    dmaA(0, 0);
    dmaA(1, 1);
    __builtin_amdgcn_sched_barrier(0);       // keep group boundary intact
    dmaB(1, 1);
    dmaA(2, 2);
    __builtin_amdgcn_sched_barrier(0);
    asm volatile("s_waitcnt vmcnt(9)" ::: "memory");
    __builtin_amdgcn_s_barrier();

    // Steady state: iter c issues g(c) = [B(c+2) x8, A(c+3) x1]; vmcnt(18)
    // drains g(c-2) = [B(c) (read now, wave-private), A(c+1) (read next iter,
    // after this iter's barrier)]. Tail iters issue clamped redundant loads so
    // every group has exactly 9 ops and the invariant needs no special cases
    // (clamped stores land in stages whose last reader already passed a
    // barrier — WAR-safe; they are drained before the epilogue).
    for (int c = 0; c < NC; ++c) {
        const int cB = (c + 2 < NC) ? c + 2 : NC - 1;
        const int cA = (c + 3 < NC) ? c + 3 : NC - 1;
        dmaB(cB, (c + 2) % 3);
        dmaA(cA, (c + 3) & 3);
        asm volatile("s_waitcnt vmcnt(18)" ::: "memory");
        __builtin_amdgcn_sched_barrier(0);   // nothing migrates across the wait
        compute(c);
        asm volatile("s_waitcnt lgkmcnt(0)" ::: "memory");
        __builtin_amdgcn_s_barrier();
    }
    // Deterministic full drain (clamped tail DMAs) before LDS is re-aliased;
    // explicit because our inline-asm waits perturb compiler waitcnt tracking.
    asm volatile("s_waitcnt vmcnt(0) lgkmcnt(0)" ::: "memory");
    __builtin_amdgcn_sched_barrier(0);
    __builtin_amdgcn_s_barrier();

    // ---- epilogue: LDS-transpose bounce, coalesced logits, fused topk ----
    float* Lt = (float*)lds;            // [32][256] fp32 = 32 KB (aliases stages)
    #pragma unroll
    for (int mi = 0; mi < 2; ++mi)
        #pragma unroll
        for (int ni = 0; ni < 4; ++ni)
            #pragma unroll
            for (int r = 0; r < 4; ++r) {
                const int tok = mi * 16 + g4 * 4 + r;       // C/D: row = quad*4+reg
                const int col = w * 64 + ni * 16 + lane16;  // C/D: col = lane&15
                Lt[tok * N_EXP + col] = acc[mi][ni][r];
            }
    __syncthreads();

    // coalesced logits store: 8192 floats = 2048 float4, 8 per thread
    float4*       Lg  = (float4*)(logits + (size_t)tok0 * N_EXP);
    const float4* Lt4 = (const float4*)Lt;
    #pragma unroll
    for (int i = 0; i < 8; ++i) Lg[i * 256 + t] = Lt4[i * 256 + t];

    // topk: wave w handles local tokens w*8 .. w*8+7
    for (int it = 0; it < 8; ++it) {
        const int tk = w * 8 + it;
        const float4 x = ((const float4*)(Lt + tk * N_EXP))[L];
        float sc[4];
        sc[0] = 1.0f / (1.0f + expf(-x.x));
        sc[1] = 1.0f / (1.0f + expf(-x.y));
        sc[2] = 1.0f / (1.0f + expf(-x.z));
        sc[3] = 1.0f / (1.0f + expf(-x.w));

        float v1 = -1.0f, v2 = -1.0f;
        int   i1 = 0,     i2 = 0;
        #pragma unroll
        for (int j = 0; j < 4; ++j) {
            const int idx = L * 4 + j;
            if (sc[j] > v1)      { v2 = v1; i2 = i1; v1 = sc[j]; i1 = idx; }
            else if (sc[j] > v2) { v2 = sc[j]; i2 = idx; }
        }
        // butterfly merge across each 16-lane group (= 64-expert group)
        #pragma unroll
        for (int offx = 1; offx < 16; offx <<= 1) {
            const float ov1 = __shfl_xor(v1, offx);
            const int   oi1 = __shfl_xor(i1, offx);
            const float ov2 = __shfl_xor(v2, offx);
            const int   oi2 = __shfl_xor(i2, offx);
            const bool o1_beats_m1 = (ov1 > v1) || (ov1 == v1 && oi1 < i1);
            if (o1_beats_m1) {
                const bool m1_beats_o2 = (v1 > ov2) || (v1 == ov2 && i1 < oi2);
                const float nv2 = m1_beats_o2 ? v1 : ov2;
                const int   ni2 = m1_beats_o2 ? i1 : oi2;
                v1 = ov1; i1 = oi1; v2 = nv2; i2 = ni2;
            } else {
                const bool o1_beats_m2 = (ov1 > v2) || (ov1 == v2 && oi1 < i2);
                v2 = o1_beats_m2 ? ov1 : v2;
                i2 = o1_beats_m2 ? oi1 : i2;
            }
        }
        float sum = 0.0f;
        #pragma unroll
        for (int g = 0; g < 4; ++g)
            sum += __shfl(v1, g * 16) + __shfl(v2, g * 16);
        const int   src = ((L >> 1) & 3) * 16;
        const float mv1 = __shfl(v1, src);
        const float mv2 = __shfl(v2, src);
        const int   mi1 = __shfl(i1, src);
        const int   mi2 = __shfl(i2, src);
        if (L < 8) {
            const float myv = (L & 1) ? mv2 : mv1;
            const int   myi = (L & 1) ? mi2 : mi1;
            out_idx[(size_t)(tok0 + tk) * 8 + L] = (float)myi;
            out_w  [(size_t)(tok0 + tk) * 8 + L] = myv * (2.5f / (sum + 1e-10f));
        }
    }
}

// ---------------- fallback (ws too small): fp32 VALU path ----------------
constexpr int FBM = 32;
constexpr int FBK = 16;
constexpr int FNC = D_MODEL / FBK;

__global__ __launch_bounds__(256) void gate_gemm_f32(
    const float* __restrict__ H, const float* __restrict__ W,
    float* __restrict__ logits)
{
    __shared__ float As[2][FBK][FBM + 4];
    __shared__ float Bs[2][FBK][N_EXP + 1];
    const int t = threadIdx.x, tx = t & 31, ty = t >> 5;
    const int tok0 = blockIdx.x * FBM, tokA = t >> 2, kqA = t & 3;
    float4 pa, pb[4];
    float acc[4][8];
    #pragma unroll
    for (int i = 0; i < 4; ++i)
        #pragma unroll
        for (int j = 0; j < 8; ++j) acc[i][j] = 0.0f;
    auto issue_loads = [&](int kc) {
        if (t < 128) pa = *(const float4*)(H + (size_t)(tok0 + tokA) * D_MODEL + kc + kqA * 4);
        #pragma unroll
        for (int j = 0; j < 4; ++j) {
            const int flat = t + 256 * j, e = flat >> 2, kq = flat & 3;
            pb[j] = *(const float4*)(W + (size_t)e * D_MODEL + kc + kq * 4);
        }
    };
    auto write_lds = [&](int buf) {
        if (t < 128) {
            As[buf][kqA * 4 + 0][tokA] = pa.x; As[buf][kqA * 4 + 1][tokA] = pa.y;
            As[buf][kqA * 4 + 2][tokA] = pa.z; As[buf][kqA * 4 + 3][tokA] = pa.w;
        }
        #pragma unroll
        for (int j = 0; j < 4; ++j) {
            const int flat = t + 256 * j, e = flat >> 2, kq = flat & 3;
            Bs[buf][kq * 4 + 0][e] = pb[j].x; Bs[buf][kq * 4 + 1][e] = pb[j].y;
            Bs[buf][kq * 4 + 2][e] = pb[j].z; Bs[buf][kq * 4 + 3][e] = pb[j].w;
        }
    };
    issue_loads(0); write_lds(0); __syncthreads();
    for (int c = 0; c < FNC; ++c) {
        const int buf = c & 1;
        if (c + 1 < FNC) issue_loads((c + 1) * FBK);
        #pragma unroll
        for (int k = 0; k < FBK; ++k) {
            const float4 av = *(const float4*)&As[buf][k][ty * 4];
            const float a[4] = {av.x, av.y, av.z, av.w};
            float b[8];
            #pragma unroll
            for (int j = 0; j < 8; ++j) b[j] = Bs[buf][k][tx + 32 * j];
            #pragma unroll
            for (int i = 0; i < 4; ++i)
                #pragma unroll
                for (int j = 0; j < 8; ++j) acc[i][j] = fmaf(a[i], b[j], acc[i][j]);
        }
        if (c + 1 < FNC) write_lds(buf ^ 1);
        __syncthreads();
    }
    #pragma unroll
    for (int i = 0; i < 4; ++i) {
        const size_t row = (size_t)(tok0 + ty * 4 + i) * N_EXP;
        #pragma unroll
        for (int j = 0; j < 8; ++j) logits[row + tx + 32 * j] = acc[i][j];
    }
}

__global__ __launch_bounds__(256) void topk_only(
    const float* __restrict__ logits,
    float* __restrict__ out_idx, float* __restrict__ out_w)
{
    const int token = blockIdx.x * 4 + (threadIdx.x >> 6);
    const int lane  = threadIdx.x & 63;
    const float4 x = *(const float4*)(logits + (size_t)token * N_EXP + lane * 4);
    float sc[4];
    sc[0] = 1.0f / (1.0f + expf(-x.x)); sc[1] = 1.0f / (1.0f + expf(-x.y));
    sc[2] = 1.0f / (1.0f + expf(-x.z)); sc[3] = 1.0f / (1.0f + expf(-x.w));
    float v1 = -1.0f, v2 = -1.0f; int i1 = 0, i2 = 0;
    #pragma unroll
    for (int j = 0; j < 4; ++j) {
        const int idx = lane * 4 + j;
        if (sc[j] > v1)      { v2 = v1; i2 = i1; v1 = sc[j]; i1 = idx; }
        else if (sc[j] > v2) { v2 = sc[j]; i2 = idx; }
    }
    #pragma unroll
    for (int offx = 1; offx < 16; offx <<= 1) {
        const float ov1 = __shfl_xor(v1, offx); const int oi1 = __shfl_xor(i1, offx);
        const float ov2 = __shfl_xor(v2, offx); const int oi2 = __shfl_xor(i2, offx);
        const bool o1_beats_m1 = (ov1 > v1) || (ov1 == v1 && oi1 < i1);
        if (o1_beats_m1) {
            const bool m1_beats_o2 = (v1 > ov2) || (v1 == ov2 && i1 < oi2);
            const float nv2 = m1_beats_o2 ? v1 : ov2;
            const int   ni2 = m1_beats_o2 ? i1 : oi2;
            v1 = ov1; i1 = oi1; v2 = nv2; i2 = ni2;
        } else {
            const bool o1_beats_m2 = (ov1 > v2) || (ov1 == v2 && oi1 < i2);
            v2 = o1_beats_m2 ? ov1 : v2; i2 = o1_beats_m2 ? oi1 : i2;
        }
    }
    float sum = 0.0f;
    #pragma unroll
    for (int g = 0; g < 4; ++g) sum += __shfl(v1, g * 16) + __shfl(v2, g * 16);
    const int src = ((lane >> 1) & 3) * 16;
    const float mv1 = __shfl(v1, src), mv2 = __shfl(v2, src);
    const int   mi1 = __shfl(i1, src), mi2 = __shfl(i2, src);
    if (lane < 8) {
        const float myv = (lane & 1) ? mv2 : mv1;
        const int   myi = (lane & 1) ? mi2 : mi1;
        out_idx[(size_t)token * 8 + lane] = (float)myi;
        out_w  [(size_t)token * 8 + lane] = myv * (2.5f / (sum + 1e-10f));
    }
}

extern "C" void kernel_launch(void* const* d_in, const int* in_sizes, int n_in,
                              void* d_out, int out_size, void* d_ws, size_t ws_size,
                              hipStream_t stream) {
    const float* H = (const float*)d_in[0];   // hidden_states [8192, 4096]
    const float* W = (const float*)d_in[1];   // gate_w        [256, 4096]

    float* out     = (float*)d_out;
    float* out_idx = out;                           // 8192*8
    float* out_w   = out + (size_t)N_TOKENS * 8;    // 8192*8
    float* logits  = out + (size_t)N_TOKENS * 16;   // 8192*256

    if (ws_size >= WS_NEED) {
        unsigned short* wsB = (unsigned short*)d_ws;
        static bool attr_done = []() {
            hipFuncSetAttribute((const void*)gate_fused,
                                hipFuncAttributeMaxDynamicSharedMemorySize,
                                (int)LDS_BYTES);
            return true;
        }();
        (void)attr_done;
        convert_w<<<dim3(NC * 4), dim3(256), 0, stream>>>(W, wsB);
        gate_fused<<<dim3(N_TOKENS / BM), dim3(256), LDS_BYTES, stream>>>(
            H, wsB, logits, out_idx, out_w);
    } else {
        gate_gemm_f32<<<dim3(N_TOKENS / FBM), dim3(256), 0, stream>>>(H, W, logits);
        topk_only<<<dim3(N_TOKENS / 4), dim3(256), 0, stream>>>(logits, out_idx, out_w);
    }
}